// Round 6
// baseline (259.103 us; speedup 1.0000x reference)
//
#include <hip/hip_runtime.h>
#include <math.h>

#define H 16
#define B 4
#define S 1024
#define E 1024
#define DK 64

typedef _Float16 f16x8 __attribute__((ext_vector_type(8)));
typedef _Float16 f16x4 __attribute__((ext_vector_type(4)));
typedef float    f32x4 __attribute__((ext_vector_type(4)));

// XOR-swizzle for [r][64 f16] tiles (128B row stride) — used by reg-staged
// kernels (attn, cvt) only. gload_lds kernels use linear LDS + pre-swizzled
// per-lane global source (rule #21: source perm == read perm).
__device__ __forceinline__ int swzb(int row, int colByte) {
    return row * 128 + (colByte ^ ((row & 7) << 4));
}

// ---------------------------------------------------------------------------
// emb f32 -> embH + embL f16 (double-f16 split). 8 elems/thread.
// ---------------------------------------------------------------------------
__global__ __launch_bounds__(256) void cvt_split_emb(const float* __restrict__ in,
                                                     _Float16* __restrict__ outH,
                                                     _Float16* __restrict__ outL) {
    int i = (blockIdx.x * 256 + threadIdx.x) * 8;
    float4 a = *(const float4*)&in[i];
    float4 b = *(const float4*)&in[i + 4];
    float x[8] = {a.x, a.y, a.z, a.w, b.x, b.y, b.z, b.w};
    f16x8 h, l;
    #pragma unroll
    for (int j = 0; j < 8; ++j) {
        _Float16 hh = (_Float16)x[j];
        h[j] = hh;
        l[j] = (_Float16)(x[j] - (float)hh);
    }
    *(f16x8*)&outH[i] = h;
    *(f16x8*)&outL[i] = l;
}

// ---------------------------------------------------------------------------
// Merged weight conversion.
// y<48: Wq/Wk/Wv [h][e][d] -> WTh [n][e] (+WTl for n<2048), transposed+split.
// y>=48: Wo [k][n] -> WoT [n][k], f16.
// grid (16, 64)
// ---------------------------------------------------------------------------
__global__ __launch_bounds__(256) void cvt_weights(
    const float* __restrict__ Wq, const float* __restrict__ Wk,
    const float* __restrict__ Wv, const float* __restrict__ Wo,
    _Float16* __restrict__ WTh, _Float16* __restrict__ WTl,
    _Float16* __restrict__ WoT) {
    __shared__ _Float16 Th[64 * 64];
    __shared__ _Float16 Tl[64 * 64];
    int tid = threadIdx.x;
    if (blockIdx.y < 48) {
        int et = blockIdx.x, chunk = blockIdx.y;
        const float* W = (chunk < 16 ? Wq : chunk < 32 ? Wk : Wv)
                         + (size_t)(chunk & 15) * E * DK;
        #pragma unroll
        for (int rr = 0; rr < 4; ++rr) {
            int u = rr * 256 + tid;
            int ei = u >> 4, f4 = u & 15;
            float4 v = *(const float4*)&W[(size_t)(et * 64 + ei) * 64 + f4 * 4];
            float x[4] = {v.x, v.y, v.z, v.w};
            f16x4 h, l;
            #pragma unroll
            for (int j = 0; j < 4; ++j) {
                _Float16 hh = (_Float16)x[j];
                h[j] = hh;
                l[j] = (_Float16)(x[j] - (float)hh);
            }
            *(f16x4*)((char*)Th + swzb(ei, f4 * 8)) = h;
            *(f16x4*)((char*)Tl + swzb(ei, f4 * 8)) = l;
        }
        __syncthreads();
        #pragma unroll
        for (int rr = 0; rr < 2; ++rr) {
            int u = rr * 256 + tid;
            int d = u >> 3, e8 = u & 7;
            f16x8 oh, ol;
            #pragma unroll
            for (int j = 0; j < 8; ++j) {
                int ei = e8 * 8 + j;
                oh[j] = *(_Float16*)((char*)Th + swzb(ei, d * 2));
                ol[j] = *(_Float16*)((char*)Tl + swzb(ei, d * 2));
            }
            size_t idx = (size_t)(chunk * 64 + d) * 1024 + et * 64 + e8 * 8;
            *(f16x8*)&WTh[idx] = oh;
            if (chunk < 32) *(f16x8*)&WTl[idx] = ol;
        }
    } else {
        int kt = blockIdx.x, nt = blockIdx.y - 48;
        #pragma unroll
        for (int rr = 0; rr < 4; ++rr) {
            int u = rr * 256 + tid;
            int ki = u >> 4, f4 = u & 15;
            float4 v = *(const float4*)&Wo[(size_t)(kt * 64 + ki) * 1024 + nt * 64 + f4 * 4];
            f16x4 o = { (_Float16)v.x, (_Float16)v.y, (_Float16)v.z, (_Float16)v.w };
            *(f16x4*)((char*)Th + swzb(ki, f4 * 8)) = o;
        }
        __syncthreads();
        #pragma unroll
        for (int rr = 0; rr < 2; ++rr) {
            int u = rr * 256 + tid;
            int nl = u >> 3, k8 = u & 7;
            f16x8 o;
            #pragma unroll
            for (int j = 0; j < 8; ++j) {
                int ki = k8 * 8 + j;
                o[j] = *(_Float16*)((char*)Th + swzb(ki, nl * 2));
            }
            *(f16x8*)&WoT[(size_t)(nt * 64 + nl) * 1024 + kt * 64 + k8 * 8] = o;
        }
    }
}

// ---------------------------------------------------------------------------
// Fused QKV projection GEMM. grid 768 = 32 mt x 24 nt (XCD-swizzled).
// nt<16: Q,K double-f16 (3-term MFMA), BK=32. LDS rows are 128B with H
//   chunks in slots 0-3 and L chunks in slots 4-7, slot s <- chunk s^(row&7)
//   via per-lane source swizzle -> conflict-free b128 frag reads.
// nt>=16: V single-term, BK=64, pure-H rows, same 8-slot swizzle.
// Epilogues: Q->QbH/QbL [hb][s][dk]; K->kkTH/kkTL [hb][d][t] (reshaped-K);
// V->V2 [hb][dv][t] (pre-transposed).
// ---------------------------------------------------------------------------
__global__ __launch_bounds__(256) void gemm_qkv(
    const _Float16* __restrict__ AH, const _Float16* __restrict__ AL,
    const _Float16* __restrict__ BTh, const _Float16* __restrict__ BTl,
    _Float16* __restrict__ QbH, _Float16* __restrict__ QbL,
    _Float16* __restrict__ kkTH, _Float16* __restrict__ kkTL,
    _Float16* __restrict__ V2) {
    __shared__ _Float16 SA[128 * 64];
    __shared__ _Float16 SB[128 * 64];
    int wg = ((int)blockIdx.x & 7) * 96 + ((int)blockIdx.x >> 3);  // 768%8==0
    int mt = wg / 24, nt = wg % 24;
    int r0 = mt * 128;
    int tid = threadIdx.x, lane = tid & 63, w = tid >> 6;
    int wr = w >> 1, wc = w & 1;
    int l15 = lane & 15, l4 = lane >> 4;

    f32x4 zero = {0.f, 0.f, 0.f, 0.f};
    f32x4 acc[4][4];
    #pragma unroll
    for (int i = 0; i < 4; ++i)
        #pragma unroll
        for (int j = 0; j < 4; ++j) acc[i][j] = zero;

    if (nt < 16) {
        // ---------------- Q,K path (double-f16, BK=32) ----------------
        int c0 = nt * 128;
        for (int kt = 0; kt < 32; ++kt) {
            __syncthreads();
            #pragma unroll
            for (int rr = 0; rr < 4; ++rr) {
                int u = rr * 256 + tid;
                int row = u >> 3, slot = u & 7;
                int c = slot ^ (row & 7);          // source chunk (H:0-3, L:4-7)
                size_t kofs = (size_t)1024 * row + kt * 32 + (c & 3) * 8;
                const _Float16* sa = (c < 4 ? AH : AL) + (size_t)r0 * 1024 + kofs;
                const _Float16* sb = (c < 4 ? BTh : BTl) + (size_t)c0 * 1024 + kofs;
                __builtin_amdgcn_global_load_lds(sa, &SA[u * 8], 16, 0, 0);
                __builtin_amdgcn_global_load_lds(sb, &SB[u * 8], 16, 0, 0);
            }
            __syncthreads();

            f16x8 afH[4], afL[4], bfH[4], bfL[4];
            #pragma unroll
            for (int f = 0; f < 4; ++f) {
                int ar = wr * 64 + f * 16 + l15;
                int br = wc * 64 + f * 16 + l15;
                afH[f] = *(const f16x8*)((char*)SA + ar * 128 + ((l4    ) ^ (ar & 7)) * 16);
                afL[f] = *(const f16x8*)((char*)SA + ar * 128 + ((l4 + 4) ^ (ar & 7)) * 16);
                bfH[f] = *(const f16x8*)((char*)SB + br * 128 + ((l4    ) ^ (br & 7)) * 16);
                bfL[f] = *(const f16x8*)((char*)SB + br * 128 + ((l4 + 4) ^ (br & 7)) * 16);
            }
            #pragma unroll
            for (int i = 0; i < 4; ++i)
                #pragma unroll
                for (int j = 0; j < 4; ++j) {
                    acc[i][j] = __builtin_amdgcn_mfma_f32_16x16x32_f16(
                        afH[i], bfH[j], acc[i][j], 0, 0, 0);
                    acc[i][j] = __builtin_amdgcn_mfma_f32_16x16x32_f16(
                        afH[i], bfL[j], acc[i][j], 0, 0, 0);
                    acc[i][j] = __builtin_amdgcn_mfma_f32_16x16x32_f16(
                        afL[i], bfH[j], acc[i][j], 0, 0, 0);
                }
        }

        #pragma unroll
        for (int i = 0; i < 4; ++i) {
            int grow0 = r0 + wr * 64 + i * 16 + l4 * 4;
            #pragma unroll
            for (int j = 0; j < 4; ++j) {
                int gcol = c0 + wc * 64 + j * 16 + l15;
                if (gcol < 1024) {                       // ---- Q (split) ----
                    int hh = gcol >> 6, dk = gcol & 63;
                    #pragma unroll
                    for (int r = 0; r < 4; ++r) {
                        int grow = grow0 + r;
                        int bb = grow >> 10, s = grow & 1023;
                        float v = acc[i][j][r];
                        _Float16 h = (_Float16)v;
                        size_t idx = (((size_t)hh * 4 + bb) * 1024 + s) * 64 + dk;
                        QbH[idx] = h;
                        QbL[idx] = (_Float16)(v - (float)h);
                    }
                } else {                                 // ---- K (split, reshaped) ----
                    int hh = (gcol >> 6) & 15, dk = gcol & 63;
                    #pragma unroll
                    for (int r = 0; r < 4; ++r) {
                        int grow = grow0 + r;
                        int bb = grow >> 10, s = grow & 1023;
                        float v = acc[i][j][r];
                        _Float16 h = (_Float16)v;
                        size_t idx = (((size_t)hh * 4 + bb) * 64 + (s >> 4)) * 1024
                                     + (s & 15) * 64 + dk;
                        kkTH[idx] = h;
                        kkTL[idx] = (_Float16)(v - (float)h);
                    }
                }
            }
        }
    } else {
        // ---------------- V path (single f16, BK=64) ----------------
        int c0 = 2048 + (nt - 16) * 128;
        for (int kt = 0; kt < 16; ++kt) {
            __syncthreads();
            #pragma unroll
            for (int rr = 0; rr < 4; ++rr) {
                int u = rr * 256 + tid;
                int row = u >> 3, slot = u & 7;
                int c = slot ^ (row & 7);
                size_t ga = (size_t)(r0 + row) * 1024 + kt * 64 + c * 8;
                size_t gb = (size_t)(c0 + row) * 1024 + kt * 64 + c * 8;
                __builtin_amdgcn_global_load_lds(&AH[ga],  &SA[u * 8], 16, 0, 0);
                __builtin_amdgcn_global_load_lds(&BTh[gb], &SB[u * 8], 16, 0, 0);
            }
            __syncthreads();

            #pragma unroll
            for (int ks = 0; ks < 2; ++ks) {
                f16x8 af[4], bf[4];
                #pragma unroll
                for (int f = 0; f < 4; ++f) {
                    int ar = wr * 64 + f * 16 + l15;
                    int br = wc * 64 + f * 16 + l15;
                    af[f] = *(const f16x8*)((char*)SA + ar * 128 + ((ks * 4 + l4) ^ (ar & 7)) * 16);
                    bf[f] = *(const f16x8*)((char*)SB + br * 128 + ((ks * 4 + l4) ^ (br & 7)) * 16);
                }
                #pragma unroll
                for (int i = 0; i < 4; ++i)
                    #pragma unroll
                    for (int j = 0; j < 4; ++j)
                        acc[i][j] = __builtin_amdgcn_mfma_f32_16x16x32_f16(
                            af[i], bf[j], acc[i][j], 0, 0, 0);
            }
        }

        #pragma unroll
        for (int i = 0; i < 4; ++i) {
            int grow0 = r0 + wr * 64 + i * 16 + l4 * 4;
            int bb = grow0 >> 10, s = grow0 & 1023;
            #pragma unroll
            for (int j = 0; j < 4; ++j) {
                int gcol = c0 + wc * 64 + j * 16 + l15;
                int hh = (gcol >> 6) & 15, dv = gcol & 63;
                f16x4 o = { (_Float16)acc[i][j][0], (_Float16)acc[i][j][1],
                            (_Float16)acc[i][j][2], (_Float16)acc[i][j][3] };
                *(f16x4*)&V2[(((size_t)hh * 4 + bb) * 64 + dv) * 1024 + s] = o;
            }
        }
    }
}

// ---------------------------------------------------------------------------
// kkT [hb][64 d][1024 t] -> K2 [hb][1024 t][64 d], modes: 0=hi, 1=lo.
// ---------------------------------------------------------------------------
__global__ __launch_bounds__(256) void trans_k(const _Float16* __restrict__ kkTH,
                                               const _Float16* __restrict__ kkTL,
                                               _Float16* __restrict__ K2H,
                                               _Float16* __restrict__ K2L) {
    int tt = blockIdx.x;
    size_t hb = blockIdx.y;
    int mode = blockIdx.z;
    const _Float16* src = mode ? kkTL : kkTH;
    _Float16* dst = mode ? K2L : K2H;
    __shared__ _Float16 T[64 * 64];
    int tid = threadIdx.x;
    #pragma unroll
    for (int rr = 0; rr < 2; ++rr) {
        int u = rr * 256 + tid;
        int d = u >> 3, c8 = u & 7;
        f16x8 v = *(const f16x8*)&src[(hb * 64 + d) * 1024 + tt * 64 + c8 * 8];
        *(f16x8*)((char*)T + swzb(d, c8 * 16)) = v;
    }
    __syncthreads();
    #pragma unroll
    for (int rr = 0; rr < 2; ++rr) {
        int u = rr * 256 + tid;
        int ti = u >> 3, d8 = u & 7;
        f16x8 o;
        #pragma unroll
        for (int j = 0; j < 8; ++j)
            o[j] = *(_Float16*)((char*)T + swzb(d8 * 8 + j, ti * 2));
        *(f16x8*)&dst[(hb * 1024 + tt * 64 + ti) * 64 + d8 * 8] = o;
    }
}

// ---------------------------------------------------------------------------
// Flash attention, double-f16 QK^T (3 terms). T14 async staging, LPT order,
// setprio around MFMA clusters. Output -> scrambled concat CC, f16.
// ---------------------------------------------------------------------------
__global__ __launch_bounds__(256) void attn(
    const _Float16* __restrict__ QbH, const _Float16* __restrict__ QbL,
    const _Float16* __restrict__ K2H, const _Float16* __restrict__ K2L,
    const _Float16* __restrict__ V2, _Float16* __restrict__ CC) {
    int qt = 15 - (int)blockIdx.x;       // LPT: long blocks dispatch first
    int b = blockIdx.y, h = blockIdx.z;
    size_t hb = (size_t)h * 4 + b;
    __shared__ _Float16 QsH[64 * 64], QsL[64 * 64];
    __shared__ _Float16 KsH[64 * 64], KsL[64 * 64];
    __shared__ _Float16 Vs[64 * 64], Ps[64 * 64];
    int tid = threadIdx.x, lane = tid & 63, w = tid >> 6;
    int l15 = lane & 15, l4 = lane >> 4;
    int s0 = qt * 64;

    // stage Q (reg -> swizzled LDS)
    #pragma unroll
    for (int rr = 0; rr < 2; ++rr) {
        int u = rr * 256 + tid, row = u >> 3, c8 = u & 7;
        size_t gi = (hb * 1024 + s0 + row) * 64 + c8 * 8;
        int off = swzb(row, c8 * 16);
        *(f16x8*)((char*)QsH + off) = *(const f16x8*)&QbH[gi];
        *(f16x8*)((char*)QsL + off) = *(const f16x8*)&QbL[gi];
    }
    // prologue: load tile 0 into regs
    f16x8 rkH[2], rkL[2], rv[2];
    #pragma unroll
    for (int rr = 0; rr < 2; ++rr) {
        int u = rr * 256 + tid, row = u >> 3, c8 = u & 7;
        size_t ki = (hb * 1024 + row) * 64 + c8 * 8;
        rkH[rr] = *(const f16x8*)&K2H[ki];
        rkL[rr] = *(const f16x8*)&K2L[ki];
        rv[rr]  = *(const f16x8*)&V2[(hb * 64 + row) * 1024 + c8 * 8];
    }
    __syncthreads();
    int srow = w * 16 + l15;
    f16x8 qfH[2], qfL[2];
    #pragma unroll
    for (int ks = 0; ks < 2; ++ks) {
        int kb = (ks * 32 + l4 * 8) * 2;
        qfH[ks] = *(const f16x8*)((char*)QsH + swzb(srow, kb));
        qfL[ks] = *(const f16x8*)((char*)QsL + swzb(srow, kb));
    }

    float m = -__builtin_inff(), lsum = 0.f;
    f32x4 zero = {0.f, 0.f, 0.f, 0.f};
    f32x4 acc2[4] = {zero, zero, zero, zero};
    int sg = s0 + srow;
    int ntile = qt + 1;

    for (int tt = 0; tt < ntile; ++tt) {
        int t0 = tt * 64;
        __syncthreads();                 // prev tile's LDS reads done
        #pragma unroll
        for (int rr = 0; rr < 2; ++rr) { // write current tile from regs
            int u = rr * 256 + tid, row = u >> 3, c8 = u & 7;
            int off = swzb(row, c8 * 16);
            *(f16x8*)((char*)KsH + off) = rkH[rr];
            *(f16x8*)((char*)KsL + off) = rkL[rr];
            *(f16x8*)((char*)Vs + off)  = rv[rr];
        }
        if (tt + 1 < ntile) {            // issue next-tile loads (in flight
            int t0n = t0 + 64;           // during this tile's compute)
            #pragma unroll
            for (int rr = 0; rr < 2; ++rr) {
                int u = rr * 256 + tid, row = u >> 3, c8 = u & 7;
                size_t ki = (hb * 1024 + t0n + row) * 64 + c8 * 8;
                rkH[rr] = *(const f16x8*)&K2H[ki];
                rkL[rr] = *(const f16x8*)&K2L[ki];
                rv[rr]  = *(const f16x8*)&V2[(hb * 64 + row) * 1024 + t0n + c8 * 8];
            }
        }
        __syncthreads();

        f32x4 z[4] = {zero, zero, zero, zero};
        __builtin_amdgcn_s_setprio(1);
        #pragma unroll
        for (int ks = 0; ks < 2; ++ks) {
            int kb = (ks * 32 + l4 * 8) * 2;
            #pragma unroll
            for (int f = 0; f < 4; ++f) {
                int trow = f * 16 + l15;
                f16x8 akH = *(const f16x8*)((char*)KsH + swzb(trow, kb));
                f16x8 akL = *(const f16x8*)((char*)KsL + swzb(trow, kb));
                z[f] = __builtin_amdgcn_mfma_f32_16x16x32_f16(akH, qfH[ks], z[f], 0, 0, 0);
                z[f] = __builtin_amdgcn_mfma_f32_16x16x32_f16(akH, qfL[ks], z[f], 0, 0, 0);
                z[f] = __builtin_amdgcn_mfma_f32_16x16x32_f16(akL, qfH[ks], z[f], 0, 0, 0);
            }
        }
        __builtin_amdgcn_s_setprio(0);
        // scale + causal mask + lane-local row max
        float mt = -__builtin_inff();
        #pragma unroll
        for (int f = 0; f < 4; ++f)
            #pragma unroll
            for (int r = 0; r < 4; ++r) {
                int tg = t0 + f * 16 + l4 * 4 + r;
                float val = z[f][r] * 0.125f;
                val = (tg > sg) ? -__builtin_inff() : val;
                z[f][r] = val;
                mt = fmaxf(mt, val);
            }
        mt = fmaxf(mt, __shfl_xor(mt, 16));
        mt = fmaxf(mt, __shfl_xor(mt, 32));
        float mn = fmaxf(m, mt);
        float corr = __expf(m - mn);
        float ps = 0.f;
        #pragma unroll
        for (int f = 0; f < 4; ++f)
            #pragma unroll
            for (int r = 0; r < 4; ++r) {
                float p = __expf(z[f][r] - mn);
                z[f][r] = p;
                ps += p;
            }
        ps += __shfl_xor(ps, 16);
        ps += __shfl_xor(ps, 32);
        lsum = lsum * corr + ps;
        m = mn;
        #pragma unroll
        for (int f = 0; f < 4; ++f) acc2[f] *= corr;

        // P^T -> Ps (wave-private rows, no barrier needed)
        #pragma unroll
        for (int f = 0; f < 4; ++f) {
            f16x4 pk = { (_Float16)z[f][0], (_Float16)z[f][1],
                         (_Float16)z[f][2], (_Float16)z[f][3] };
            *(f16x4*)((char*)Ps + swzb(srow, (f * 16 + l4 * 4) * 2)) = pk;
        }
        __builtin_amdgcn_s_setprio(1);
        #pragma unroll
        for (int ks = 0; ks < 2; ++ks) {
            int kb = (ks * 32 + l4 * 8) * 2;
            f16x8 bp = *(const f16x8*)((char*)Ps + swzb(srow, kb));
            #pragma unroll
            for (int f = 0; f < 4; ++f) {
                int dvrow = f * 16 + l15;
                f16x8 av = *(const f16x8*)((char*)Vs + swzb(dvrow, kb));
                acc2[f] = __builtin_amdgcn_mfma_f32_16x16x32_f16(av, bp, acc2[f], 0, 0, 0);
            }
        }
        __builtin_amdgcn_s_setprio(0);
    }

    float inv = 1.f / lsum;
    int sp = s0 + srow;
    int bprow = h >> 2;
    int spp = (h & 3) * 256 + b * 64 + (sp >> 4);
    int cb = (sp & 15) * 64;
    #pragma unroll
    for (int f = 0; f < 4; ++f) {
        int dv = f * 16 + l4 * 4;
        f16x4 o = { (_Float16)(acc2[f][0] * inv), (_Float16)(acc2[f][1] * inv),
                    (_Float16)(acc2[f][2] * inv), (_Float16)(acc2[f][3] * inv) };
        *(f16x4*)&CC[((size_t)bprow * 1024 + spp) * 1024 + cb + dv] = o;
    }
}

// ---------------------------------------------------------------------------
// Output projection: CC[4096][1024] @ WoT[1024][1024]^T -> out f32.
// m97 structure + conflict-free source-swizzle (BK=64, 8-slot rows).
// ---------------------------------------------------------------------------
__global__ __launch_bounds__(256) void gemm_out(
    const _Float16* __restrict__ A, const _Float16* __restrict__ BT,
    float* __restrict__ out) {
    __shared__ _Float16 As[128 * 64];
    __shared__ _Float16 Bs[128 * 64];
    int wg = ((int)blockIdx.x & 7) * 32 + ((int)blockIdx.x >> 3);
    int mt = wg >> 3, nt = wg & 7;
    int r0 = mt * 128, c0 = nt * 128;
    int tid = threadIdx.x, lane = tid & 63, w = tid >> 6;
    int wr = w >> 1, wc = w & 1;
    int l15 = lane & 15, l4 = lane >> 4;

    f32x4 zero = {0.f, 0.f, 0.f, 0.f};
    f32x4 acc[4][4];
    #pragma unroll
    for (int i = 0; i < 4; ++i)
        #pragma unroll
        for (int j = 0; j < 4; ++j) acc[i][j] = zero;

    for (int kt = 0; kt < 16; ++kt) {
        __syncthreads();
        #pragma unroll
        for (int rr = 0; rr < 4; ++rr) {
            int u = rr * 256 + tid;
            int row = u >> 3, slot = u & 7;
            int c = slot ^ (row & 7);
            size_t ga = (size_t)(r0 + row) * 1024 + kt * 64 + c * 8;
            size_t gb = (size_t)(c0 + row) * 1024 + kt * 64 + c * 8;
            __builtin_amdgcn_global_load_lds(&A[ga],  &As[u * 8], 16, 0, 0);
            __builtin_amdgcn_global_load_lds(&BT[gb], &Bs[u * 8], 16, 0, 0);
        }
        __syncthreads();

        #pragma unroll
        for (int ks = 0; ks < 2; ++ks) {
            f16x8 af[4], bf[4];
            #pragma unroll
            for (int f = 0; f < 4; ++f) {
                int ar = wr * 64 + f * 16 + l15;
                int br = wc * 64 + f * 16 + l15;
                af[f] = *(const f16x8*)((char*)As + ar * 128 + ((ks * 4 + l4) ^ (ar & 7)) * 16);
                bf[f] = *(const f16x8*)((char*)Bs + br * 128 + ((ks * 4 + l4) ^ (br & 7)) * 16);
            }
            #pragma unroll
            for (int i = 0; i < 4; ++i)
                #pragma unroll
                for (int j = 0; j < 4; ++j)
                    acc[i][j] = __builtin_amdgcn_mfma_f32_16x16x32_f16(
                        af[i], bf[j], acc[i][j], 0, 0, 0);
        }
    }

    #pragma unroll
    for (int i = 0; i < 4; ++i) {
        int grow0 = r0 + wr * 64 + i * 16 + l4 * 4;
        #pragma unroll
        for (int j = 0; j < 4; ++j) {
            int gcol = c0 + wc * 64 + j * 16 + l15;
            #pragma unroll
            for (int r = 0; r < 4; ++r)
                out[(size_t)(grow0 + r) * 1024 + gcol] = acc[i][j][r];
        }
    }
}

// ---------------------------------------------------------------------------
extern "C" void kernel_launch(void* const* d_in, const int* in_sizes, int n_in,
                              void* d_out, int out_size, void* d_ws, size_t ws_size,
                              hipStream_t stream) {
    const float* emb = (const float*)d_in[0];
    const float* Wq  = (const float*)d_in[1];
    const float* Wk  = (const float*)d_in[2];
    const float* Wv  = (const float*)d_in[3];
    const float* Wo  = (const float*)d_in[4];
    float* out = (float*)d_out;

    // ws: 52 MB with aliasing (lifetimes checked against stream order)
    _Float16* embH = (_Float16*)d_ws;          // 4M f16   [K2H aliases later]
    _Float16* embL = embH + 4194304;           // 4M       [K2L aliases later]
    _Float16* WTh  = embL + 4194304;           // 3M       [CC aliases later]
    _Float16* WTl  = WTh + 3145728;            // 2M
    _Float16* WoT  = WTl + 2097152;            // 1M
    _Float16* QbH  = WoT + 1048576;            // 4M
    _Float16* QbL  = QbH + 4194304;            // 4M
    _Float16* V2   = QbL + 4194304;            // 4M  -> total 26M f16 = 52 MB
    _Float16* K2H  = embH;                     // alias: emb dead after gemm_qkv
    _Float16* K2L  = embL;
    _Float16* CC   = WTh;                      // alias: WT dead after gemm_qkv
    // kkT hi/lo parked in d_out (16 MB), dead before gemm_out writes it
    _Float16* kkTH = (_Float16*)d_out;
    _Float16* kkTL = kkTH + 4194304;

    cvt_split_emb<<<2048, 256, 0, stream>>>(emb, embH, embL);
    cvt_weights  <<<dim3(16, 64), 256, 0, stream>>>(Wq, Wk, Wv, Wo, WTh, WTl, WoT);
    gemm_qkv     <<<768, 256, 0, stream>>>(embH, embL, WTh, WTl,
                                           QbH, QbL, kkTH, kkTL, V2);
    trans_k      <<<dim3(16, 64, 2), 256, 0, stream>>>(kkTH, kkTL, K2H, K2L);
    attn         <<<dim3(16, 4, 16), 256, 0, stream>>>(QbH, QbL, K2H, K2L, V2, CC);
    gemm_out     <<<256, 256, 0, stream>>>(CC, WoT, out);
}